// Round 1
// baseline (221.475 us; speedup 1.0000x reference)
//
#include <hip/hip_runtime.h>
#include <cstddef>

// Problem constants (from reference)
constexpr int kC = 81;            // NUM_CLASSES + 1
constexpr int kNumBase = 60;      // NUM_CLASSES // 4 * 3
constexpr int kNumClasses = 80;
constexpr float kWNovel = 1.0f / 10.0f;   // 1/SHOT
constexpr float kWBase = kWNovel / 3.0f;
constexpr float kWNeg = 0.001f;
constexpr float kEpsDiff = 1e-3f;
constexpr float kMaxLog = 5.0f;
constexpr float kMaxLoss = 1.0f;
constexpr int kMinSamp = 2;

// One wave (64 lanes) per row. Lane i holds column i; lanes 0..16 also hold
// column 64+i. Softmax + margin-term row sum fully in registers via shuffles.
// Per-class (sum,count) accumulated in an 81-bin LDS histogram, then merged
// to global with atomics.
__global__ __launch_bounds__(256) void adl_main(
    const float* __restrict__ cls,
    const int* __restrict__ labels,
    const float* __restrict__ lw,
    float* __restrict__ gsum,
    int* __restrict__ gcnt,
    int n) {
  __shared__ float ssum[kC];
  __shared__ int scnt[kC];
  for (int i = threadIdx.x; i < kC; i += blockDim.x) { ssum[i] = 0.0f; scnt[i] = 0; }
  __syncthreads();

  const int lane = threadIdx.x & 63;
  const int wave = threadIdx.x >> 6;
  const int waves_per_block = blockDim.x >> 6;
  const int gwave = blockIdx.x * waves_per_block + wave;
  const int nwaves = gridDim.x * waves_per_block;
  const bool hi = (lane < kC - 64);  // lanes holding the second column

  for (int row = gwave; row < n; row += nwaves) {
    const float* rp = cls + (size_t)row * kC;
    float x0 = rp[lane];
    float x1 = hi ? rp[64 + lane] : -3.0e38f;

    // softmax max
    float m = fmaxf(x0, x1);
#pragma unroll
    for (int off = 32; off > 0; off >>= 1) m = fmaxf(m, __shfl_xor(m, off));

    // softmax denom
    float e0 = __expf(x0 - m);
    float e1 = hi ? __expf(x1 - m) : 0.0f;
    float s = e0 + e1;
#pragma unroll
    for (int off = 32; off > 0; off >>= 1) s += __shfl_xor(s, off);
    float inv = 1.0f / s;
    float p0 = e0 * inv;
    float p1 = e1 * inv;

    int label = labels[row];  // wave-uniform broadcast load
    float pa = __shfl(p0, label & 63);
    float pb = __shfl(p1, (label - 64) & 63);
    float p_true = (label < 64) ? pa : pb;

    // weight = clip(1 - p_true, 1e-4, 1)^2
    float om = fminf(fmaxf(1.0f - p_true, 1e-4f), 1.0f);
    float w = om * om;

    // per-column margin terms: min(-log(clip(p_true - p, 1e-3, 1)), 5)
    float d0 = fminf(fmaxf(p_true - p0, kEpsDiff), 1.0f);
    float t = fminf(-__logf(d0), kMaxLog);
    if (hi) {
      float d1 = fminf(fmaxf(p_true - p1, kEpsDiff), 1.0f);
      t += fminf(-__logf(d1), kMaxLog);
    }
#pragma unroll
    for (int off = 32; off > 0; off >>= 1) t += __shfl_xor(t, off);

    // True-column term is exactly w*5 (clip(0,1e-3,1)=1e-3, -log(1e-3)=6.9>5),
    // so the "sum over other columns" is w*(t - 5).
    float row_sum = w * (t - kMaxLog);

    if (lane == 0 && lw[row] > 0.0f) {
      atomicAdd(&ssum[label], row_sum);
      atomicAdd(&scnt[label], 1);
    }
  }

  __syncthreads();
  for (int i = threadIdx.x; i < kC; i += blockDim.x) {
    if (scnt[i] != 0) {
      atomicAdd(&gsum[i], ssum[i]);
      atomicAdd(&gcnt[i], scnt[i]);
    }
  }
}

// Apply the per-class MIN_SAMP filter and compute the three masked means.
__global__ void adl_final(const float* __restrict__ gsum,
                          const int* __restrict__ gcnt,
                          float* __restrict__ out) {
  if (threadIdx.x == 0 && blockIdx.x == 0) {
    double sb = 0.0, sn = 0.0, sg = 0.0;
    long long nb = 0, nn = 0, ng = 0;
    for (int c = 0; c < kNumBase; ++c)
      if (gcnt[c] >= kMinSamp) { sb += (double)gsum[c]; nb += gcnt[c]; }
    for (int c = kNumBase; c < kNumClasses; ++c)
      if (gcnt[c] >= kMinSamp) { sn += (double)gsum[c]; nn += gcnt[c]; }
    sg = (double)gsum[kNumClasses];
    ng = gcnt[kNumClasses];

    const double denom = (double)(kC - 1);
    double lb = (nb > 0) ? sb / ((double)nb * denom) * (double)kWBase : 0.0;
    double ln = (nn > 0) ? sn / ((double)nn * denom) * (double)kWNovel : 0.0;
    double lg = (ng > 0) ? sg / ((double)ng * denom) * (double)kWNeg : 0.0;

    out[0] = (float)fmin(lb, (double)kMaxLoss);
    out[1] = (float)fmin(ln, (double)kMaxLoss);
    out[2] = (float)fmin(lg, (double)kMaxLoss);
  }
}

extern "C" void kernel_launch(void* const* d_in, const int* in_sizes, int n_in,
                              void* d_out, int out_size, void* d_ws, size_t ws_size,
                              hipStream_t stream) {
  const float* cls = (const float*)d_in[0];
  const int* labels = (const int*)d_in[1];
  const float* lw = (const float*)d_in[2];
  float* out = (float*)d_out;
  const int n = in_sizes[1];  // N, from labels

  float* gsum = (float*)d_ws;
  int* gcnt = (int*)((char*)d_ws + kC * sizeof(float));

  // ws is re-poisoned to 0xAA before every call — zero our accumulators.
  hipMemsetAsync(d_ws, 0, kC * (sizeof(float) + sizeof(int)), stream);

  // 2048 blocks x 256 threads = 8192 waves (32 waves/CU), 32 rows per wave.
  adl_main<<<2048, 256, 0, stream>>>(cls, labels, lw, gsum, gcnt, n);
  adl_final<<<1, 64, 0, stream>>>(gsum, gcnt, out);
}

// Round 2
// 174.130 us; speedup vs baseline: 1.2719x; 1.2719x over previous
//
#include <hip/hip_runtime.h>
#include <cstddef>

// Problem constants (from reference)
constexpr int kC = 81;            // NUM_CLASSES + 1
constexpr int kNumBase = 60;      // NUM_CLASSES // 4 * 3
constexpr int kNumClasses = 80;
constexpr float kWNovel = 1.0f / 10.0f;   // 1/SHOT
constexpr float kWBase = kWNovel / 3.0f;
constexpr float kWNeg = 0.001f;
constexpr float kEpsDiff = 1e-3f;
constexpr float kMaxLog = 5.0f;
constexpr float kMaxLoss = 1.0f;
constexpr int kMinSamp = 2;

constexpr int kRowsPerTile = 64;                 // rows staged per block iteration
constexpr int kTileFloats = kRowsPerTile * kC;   // 5184 floats = 20.25 KB
constexpr int kTileF4 = kTileFloats / 4;         // 1296 float4s (5184 % 4 == 0)
constexpr int kColsPerLane = 21;                 // 4 lanes/row, ceil(81/4)

// Block = 256 threads (4 waves). Each block iterates over 64-row tiles:
//   stage tile into LDS with coalesced float4 loads, then 4 lanes cooperate
//   per row (21 columns each, held in VGPRs). All reductions are 2-step
//   intra-quad shuffles — no long dependent chains. Per-class (sum,count)
//   goes to an LDS histogram, flushed once per block.
__global__ __launch_bounds__(256) void adl_main(
    const float* __restrict__ cls,
    const int* __restrict__ labels,
    const float* __restrict__ lw,
    float* __restrict__ gsum,
    int* __restrict__ gcnt,
    int n) {
  __shared__ __align__(16) float sx[kTileFloats];
  __shared__ float ssum[kC];
  __shared__ int scnt[kC];

  const int tid = threadIdx.x;
  const int lane = tid & 63;
  const int wave = tid >> 6;
  if (tid < kC) { ssum[tid] = 0.0f; scnt[tid] = 0; }
  // first __syncthreads() inside the loop covers this init

  const int ntiles = n >> 6;  // N divisible by 64
  const int q = lane & 3;                       // quad index within row
  const int rloc = (wave << 4) + (lane >> 2);   // local row 0..63
  const int c0 = q * kColsPerLane;              // first column for this lane

  for (int tile = blockIdx.x; tile < ntiles; tile += gridDim.x) {
    __syncthreads();  // protect sx reuse (and initial hist init)
    // ---- stage: 1296 float4 coalesced ----
    const float4* src = (const float4*)cls + (size_t)tile * kTileF4;
    float4* dst = (float4*)sx;
#pragma unroll
    for (int i = 0; i < 5; ++i) dst[tid + i * 256] = src[tid + i * 256];
    if (tid < kTileF4 - 5 * 256) dst[tid + 5 * 256] = src[tid + 5 * 256];
    __syncthreads();

    // ---- compute: 4 lanes per row ----
    const int row = (tile << 6) + rloc;
    const float* xr = sx + rloc * kC;  // stride 81 (odd) => 2 lanes/bank, free

    float x[kColsPerLane];
#pragma unroll
    for (int j = 0; j < kColsPerLane; ++j) {
      const int c = c0 + j;
      x[j] = (c < kC) ? xr[c] : -3.0e38f;
    }

    // softmax max (tree in-thread + 2-step quad shuffle)
    float m = x[0];
#pragma unroll
    for (int j = 1; j < kColsPerLane; ++j) m = fmaxf(m, x[j]);
    m = fmaxf(m, __shfl_xor(m, 1));
    m = fmaxf(m, __shfl_xor(m, 2));

    // exp + denom
    float s = 0.0f;
#pragma unroll
    for (int j = 0; j < kColsPerLane; ++j) {
      x[j] = __expf(x[j] - m);
      s += x[j];
    }
    s += __shfl_xor(s, 1);
    s += __shfl_xor(s, 2);
    const float inv = 1.0f / s;

    const int label = labels[row];
    const float p_true = __expf(xr[label] - m) * inv;

    const float om = fminf(fmaxf(1.0f - p_true, 1e-4f), 1.0f);
    const float w = om * om;

    // margin terms: min(-log(clip(p_true - p_c, 1e-3, 1)), 5) over real cols
    float t = 0.0f;
#pragma unroll
    for (int j = 0; j < kColsPerLane; ++j) {
      const float d = fminf(fmaxf(p_true - x[j] * inv, kEpsDiff), 1.0f);
      const float term = fminf(-__logf(d), kMaxLog);
      t += (c0 + j < kC) ? term : 0.0f;
    }
    t += __shfl_xor(t, 1);
    t += __shfl_xor(t, 2);

    // True-column term is exactly 5 (clip(0,1e-3,1)=1e-3, -log(1e-3)=6.9>5),
    // so sum over the C-1 'other' columns = t - 5.
    if (q == 0) {
      if (lw[row] > 0.0f) {
        atomicAdd(&ssum[label], w * (t - kMaxLog));
        atomicAdd(&scnt[label], 1);
      }
    }
  }

  __syncthreads();
  if (tid < kC && scnt[tid] != 0) {
    atomicAdd(&gsum[tid], ssum[tid]);
    atomicAdd(&gcnt[tid], scnt[tid]);
  }
}

// One wave: lane handles classes lane and lane+64, short shuffle reductions.
__global__ __launch_bounds__(64) void adl_final(const float* __restrict__ gsum,
                                                const int* __restrict__ gcnt,
                                                float* __restrict__ out) {
  const int lane = threadIdx.x;
  float sb = 0.0f, sn = 0.0f, sg = 0.0f;
  int nb = 0, nn = 0, ng = 0;
#pragma unroll
  for (int k = 0; k < 2; ++k) {
    const int c = lane + k * 64;
    if (c < kC) {
      const int cnt = gcnt[c];
      const float sm = gsum[c];
      if (c < kNumBase) {
        if (cnt >= kMinSamp) { sb += sm; nb += cnt; }
      } else if (c < kNumClasses) {
        if (cnt >= kMinSamp) { sn += sm; nn += cnt; }
      } else {
        sg += sm; ng += cnt;
      }
    }
  }
#pragma unroll
  for (int off = 32; off > 0; off >>= 1) {
    sb += __shfl_xor(sb, off);
    sn += __shfl_xor(sn, off);
    sg += __shfl_xor(sg, off);
    nb += __shfl_xor(nb, off);
    nn += __shfl_xor(nn, off);
    ng += __shfl_xor(ng, off);
  }
  if (lane == 0) {
    const double denom = (double)(kC - 1);
    double lb = (nb > 0) ? (double)sb / ((double)nb * denom) * (double)kWBase : 0.0;
    double ln = (nn > 0) ? (double)sn / ((double)nn * denom) * (double)kWNovel : 0.0;
    double lg = (ng > 0) ? (double)sg / ((double)ng * denom) * (double)kWNeg : 0.0;
    out[0] = (float)fmin(lb, (double)kMaxLoss);
    out[1] = (float)fmin(ln, (double)kMaxLoss);
    out[2] = (float)fmin(lg, (double)kMaxLoss);
  }
}

extern "C" void kernel_launch(void* const* d_in, const int* in_sizes, int n_in,
                              void* d_out, int out_size, void* d_ws, size_t ws_size,
                              hipStream_t stream) {
  const float* cls = (const float*)d_in[0];
  const int* labels = (const int*)d_in[1];
  const float* lw = (const float*)d_in[2];
  float* out = (float*)d_out;
  const int n = in_sizes[1];  // N, from labels

  float* gsum = (float*)d_ws;
  int* gcnt = (int*)((char*)d_ws + kC * sizeof(float));

  // ws is re-poisoned to 0xAA before every call — zero our accumulators.
  hipMemsetAsync(d_ws, 0, kC * (sizeof(float) + sizeof(int)), stream);

  // 4096 tiles of 64 rows; 2048 blocks x 2 tiles each. LDS ~21 KB -> 7
  // blocks/CU resident (28 waves/CU).
  adl_main<<<2048, 256, 0, stream>>>(cls, labels, lw, gsum, gcnt, n);
  adl_final<<<1, 64, 0, stream>>>(gsum, gcnt, out);
}

// Round 3
// 128.810 us; speedup vs baseline: 1.7194x; 1.3518x over previous
//
#include <hip/hip_runtime.h>
#include <cstddef>

// Problem constants (from reference)
constexpr int kC = 81;            // NUM_CLASSES + 1
constexpr int kNumBase = 60;      // NUM_CLASSES // 4 * 3
constexpr int kNumClasses = 80;
constexpr float kWNovel = 1.0f / 10.0f;   // 1/SHOT
constexpr float kWBase = kWNovel / 3.0f;
constexpr float kWNeg = 0.001f;
constexpr float kEpsDiff = 1e-3f;
constexpr float kMaxLog = 5.0f;
constexpr float kMaxLoss = 1.0f;
constexpr int kMinSamp = 2;
constexpr int kShadows = 8;       // global-accumulator striping factor

// 16-byte vector with 4-byte alignment: lets us issue global_load_dwordx4
// from addresses that are only float-aligned (gfx9+ supports unaligned
// global vector loads).
typedef float float4u __attribute__((ext_vector_type(4), aligned(4)));

// No barriers in the hot loop, no data staging. Each wave grid-strides over
// groups of 16 rows; 4 lanes cooperate per row. Lane quad q in {0,1,2} loads
// columns [21q, 21q+21); q=3 loads [60,81) (3 columns overlap q=2 and are
// masked out of the sums with compile-time predication). All 21 values live
// in VGPRs; reductions are 2-step intra-quad shuffles. Per-class (sum,count)
// goes to a tiny LDS histogram, flushed once per block into one of 8 shadow
// copies (8x less global-atomic contention).
__global__ __launch_bounds__(256) void adl_main(
    const float* __restrict__ cls,
    const int* __restrict__ labels,
    const float* __restrict__ lw,
    float* __restrict__ gsum,
    int* __restrict__ gcnt,
    int n) {
  __shared__ float ssum[kC];
  __shared__ int scnt[kC];
  const int tid = threadIdx.x;
  if (tid < kC) { ssum[tid] = 0.0f; scnt[tid] = 0; }
  __syncthreads();

  const int lane = tid & 63;
  const int wave = tid >> 6;
  const int q = lane & 3;                  // quad index within row
  const int rsub = lane >> 2;              // row within 16-row group
  const int gw = blockIdx.x * (blockDim.x >> 6) + wave;
  const int nw = gridDim.x * (blockDim.x >> 6);
  const int ngroups = n >> 4;              // N divisible by 16
  const int c0 = (q < 3) ? q * 21 : 60;    // first column for this lane

  for (int g = gw; g < ngroups; g += nw) {
    const int row = (g << 4) + rsub;
    const float* rp = cls + (size_t)row * kC;

    // ---- load 21 columns: 5 x dwordx4 (align 4) + 1 scalar ----
    float x[21];
    const float* p = rp + c0;
#pragma unroll
    for (int k = 0; k < 5; ++k) {
      float4u v = *(const float4u*)(p + 4 * k);
      x[4 * k + 0] = v.x; x[4 * k + 1] = v.y;
      x[4 * k + 2] = v.z; x[4 * k + 3] = v.w;
    }
    x[20] = p[20];

    // ---- softmax max (duplicated cols harmless for max) ----
    float m = x[0];
#pragma unroll
    for (int j = 1; j < 21; ++j) m = fmaxf(m, x[j]);
    m = fmaxf(m, __shfl_xor(m, 1));
    m = fmaxf(m, __shfl_xor(m, 2));

    // ---- exp + denom (mask the 3 duplicated cols on q==3) ----
    float s = 0.0f;
#pragma unroll
    for (int j = 0; j < 21; ++j) {
      x[j] = __expf(x[j] - m);
      s += (j < 3 && q == 3) ? 0.0f : x[j];
    }
    s += __shfl_xor(s, 1);
    s += __shfl_xor(s, 2);
    const float inv = 1.0f / s;

    const int label = labels[row];         // 4 dup lanes/row, L1-hot
    const float p_true = __expf(rp[label] - m) * inv;  // extra L1-hot load

    const float om = fminf(fmaxf(1.0f - p_true, 1e-4f), 1.0f);
    const float w = om * om;

    // ---- margin terms: min(-log(clip(p_true - p_c, 1e-3, 1)), 5) ----
    float t = 0.0f;
#pragma unroll
    for (int j = 0; j < 21; ++j) {
      const float d = fminf(fmaxf(p_true - x[j] * inv, kEpsDiff), 1.0f);
      const float term = fminf(-__logf(d), kMaxLog);
      t += (j < 3 && q == 3) ? 0.0f : term;
    }
    t += __shfl_xor(t, 1);
    t += __shfl_xor(t, 2);

    // True-column term is exactly 5 (clip(0,1e-3,1)=1e-3, -log(1e-3)=6.9>5),
    // so the sum over the C-1 'other' columns is (t - 5).
    if (q == 0) {
      if (lw[row] > 0.0f) {
        atomicAdd(&ssum[label], w * (t - kMaxLog));
        atomicAdd(&scnt[label], 1);
      }
    }
  }

  __syncthreads();
  const int sh = blockIdx.x & (kShadows - 1);
  if (tid < kC && scnt[tid] != 0) {
    atomicAdd(&gsum[sh * kC + tid], ssum[tid]);
    atomicAdd(&gcnt[sh * kC + tid], scnt[tid]);
  }
}

// One wave: lane handles classes lane and lane+64 across the 8 shadow copies.
__global__ __launch_bounds__(64) void adl_final(const float* __restrict__ gsum,
                                                const int* __restrict__ gcnt,
                                                float* __restrict__ out) {
  const int lane = threadIdx.x;
  float sb = 0.0f, sn = 0.0f, sg = 0.0f;
  int nb = 0, nn = 0, ng = 0;
#pragma unroll
  for (int k = 0; k < 2; ++k) {
    const int c = lane + k * 64;
    if (c < kC) {
      float sm = 0.0f;
      int cnt = 0;
#pragma unroll
      for (int sh = 0; sh < kShadows; ++sh) {
        sm += gsum[sh * kC + c];
        cnt += gcnt[sh * kC + c];
      }
      if (c < kNumBase) {
        if (cnt >= kMinSamp) { sb += sm; nb += cnt; }
      } else if (c < kNumClasses) {
        if (cnt >= kMinSamp) { sn += sm; nn += cnt; }
      } else {
        sg += sm; ng += cnt;
      }
    }
  }
#pragma unroll
  for (int off = 32; off > 0; off >>= 1) {
    sb += __shfl_xor(sb, off);
    sn += __shfl_xor(sn, off);
    sg += __shfl_xor(sg, off);
    nb += __shfl_xor(nb, off);
    nn += __shfl_xor(nn, off);
    ng += __shfl_xor(ng, off);
  }
  if (lane == 0) {
    const double denom = (double)(kC - 1);
    double lb = (nb > 0) ? (double)sb / ((double)nb * denom) * (double)kWBase : 0.0;
    double ln = (nn > 0) ? (double)sn / ((double)nn * denom) * (double)kWNovel : 0.0;
    double lg = (ng > 0) ? (double)sg / ((double)ng * denom) * (double)kWNeg : 0.0;
    out[0] = (float)fmin(lb, (double)kMaxLoss);
    out[1] = (float)fmin(ln, (double)kMaxLoss);
    out[2] = (float)fmin(lg, (double)kMaxLoss);
  }
}

extern "C" void kernel_launch(void* const* d_in, const int* in_sizes, int n_in,
                              void* d_out, int out_size, void* d_ws, size_t ws_size,
                              hipStream_t stream) {
  const float* cls = (const float*)d_in[0];
  const int* labels = (const int*)d_in[1];
  const float* lw = (const float*)d_in[2];
  float* out = (float*)d_out;
  const int n = in_sizes[1];  // N, from labels

  float* gsum = (float*)d_ws;                                   // 8*81 floats
  int* gcnt = (int*)((char*)d_ws + kShadows * kC * sizeof(float));  // 8*81 ints

  // ws is re-poisoned to 0xAA before every call — zero our accumulators.
  hipMemsetAsync(d_ws, 0, kShadows * kC * (sizeof(float) + sizeof(int)), stream);

  // 2048 blocks x 256 threads = 8192 waves; 16384 16-row groups -> 2/wave.
  // LDS = 648 B, VGPR ~48 -> full 32 waves/CU occupancy, no hot-loop barriers.
  adl_main<<<2048, 256, 0, stream>>>(cls, labels, lw, gsum, gcnt, n);
  adl_final<<<1, 64, 0, stream>>>(gsum, gcnt, out);
}